// Round 3
// baseline (7998.194 us; speedup 1.0000x reference)
//
#include <hip/hip_runtime.h>
#include <math.h>

// ---------------- common types ----------------
typedef __attribute__((ext_vector_type(8))) short bf16x8;
typedef __attribute__((ext_vector_type(4))) float f32x4;
typedef __attribute__((ext_vector_type(4))) int i32x4;

__device__ __forceinline__ unsigned short f2bf(float x) {
    unsigned u = __float_as_uint(x);
    unsigned r = (u + 0x7FFF + ((u >> 16) & 1)) >> 16;
    return (unsigned short)r;
}
__device__ __forceinline__ float bf_lo(unsigned u) { return __uint_as_float(u << 16); }
__device__ __forceinline__ float bf_hi(unsigned u) { return __uint_as_float(u & 0xffff0000u); }

#define ACT_NONE  0
#define ACT_RELU  1
#define ACT_RELU2 2

// ---------------- MFMA GEMM: C[M,N] = act(A[M,K] @ B[N,K]^T + bias[N]) ----------------
// 64x64 tile, BK=32, 256 threads (4 waves, each 32x32 via 2x2 of 16x16x32 mfma).
template <int ACT, bool GATHER, bool TRANSOUT>
__global__ __launch_bounds__(256) void gemm_bt(
    const float* __restrict__ A, const float* __restrict__ Bm,
    const float* __restrict__ bias, float* __restrict__ C,
    const int* __restrict__ ids, int M, int N, int K)
{
    __shared__ unsigned short as_[64][40];
    __shared__ unsigned short bs_[64][40];

    const int tid = threadIdx.x;
    const int bm = blockIdx.x, bn = blockIdx.y;
    const int r = tid >> 2, seg = tid & 3;

    const int arow = bm * 64 + r;
    const float* aptr = GATHER ? (A + (size_t)ids[arow] * K) : (A + (size_t)arow * K);
    const float* bptr = Bm + (size_t)(bn * 64 + r) * K;

    const int w = tid >> 6, lane = tid & 63;
    const int wr = w >> 1, wc = w & 1;
    const int al = lane & 15, kq = lane >> 4;

    f32x4 acc[2][2];
    for (int mi = 0; mi < 2; ++mi)
        for (int ni = 0; ni < 2; ++ni)
            acc[mi][ni] = (f32x4){0.f, 0.f, 0.f, 0.f};

    for (int k0 = 0; k0 < K; k0 += 32) {
        __syncthreads();
        {
            const float4* ap4 = (const float4*)(aptr + k0 + seg * 8);
            float4 a0 = ap4[0], a1 = ap4[1];
            uint4 pk;
            pk.x = (unsigned)f2bf(a0.x) | ((unsigned)f2bf(a0.y) << 16);
            pk.y = (unsigned)f2bf(a0.z) | ((unsigned)f2bf(a0.w) << 16);
            pk.z = (unsigned)f2bf(a1.x) | ((unsigned)f2bf(a1.y) << 16);
            pk.w = (unsigned)f2bf(a1.z) | ((unsigned)f2bf(a1.w) << 16);
            *(uint4*)&as_[r][seg * 8] = pk;

            const float4* bp4 = (const float4*)(bptr + k0 + seg * 8);
            float4 b0 = bp4[0], b1 = bp4[1];
            pk.x = (unsigned)f2bf(b0.x) | ((unsigned)f2bf(b0.y) << 16);
            pk.y = (unsigned)f2bf(b0.z) | ((unsigned)f2bf(b0.w) << 16);
            pk.z = (unsigned)f2bf(b1.x) | ((unsigned)f2bf(b1.y) << 16);
            pk.w = (unsigned)f2bf(b1.z) | ((unsigned)f2bf(b1.w) << 16);
            *(uint4*)&bs_[r][seg * 8] = pk;
        }
        __syncthreads();

        bf16x8 af[2], bfr[2];
        af[0]  = *(const bf16x8*)&as_[wr * 32 + al][kq * 8];
        af[1]  = *(const bf16x8*)&as_[wr * 32 + 16 + al][kq * 8];
        bfr[0] = *(const bf16x8*)&bs_[wc * 32 + al][kq * 8];
        bfr[1] = *(const bf16x8*)&bs_[wc * 32 + 16 + al][kq * 8];

        for (int mi = 0; mi < 2; ++mi)
            for (int ni = 0; ni < 2; ++ni)
                acc[mi][ni] = __builtin_amdgcn_mfma_f32_16x16x32_bf16(
                    af[mi], bfr[ni], acc[mi][ni], 0, 0, 0);
    }

    for (int mi = 0; mi < 2; ++mi) {
        for (int ni = 0; ni < 2; ++ni) {
            const int gcol = bn * 64 + wc * 32 + ni * 16 + al;
            const float bv = bias ? bias[gcol] : 0.f;
            for (int i = 0; i < 4; ++i) {
                const int grow = bm * 64 + wr * 32 + mi * 16 + kq * 4 + i;
                float v = acc[mi][ni][i] + bv;
                if (ACT == ACT_RELU)  v = fmaxf(v, 0.f);
                if (ACT == ACT_RELU2) { v = fmaxf(v, 0.f); v = v * v; }
                if (TRANSOUT) {
                    const int b = grow >> 10, s = grow & 1023;
                    C[((size_t)b * N + gcol) * 1024 + s] = v;
                } else {
                    C[(size_t)grow * N + gcol] = v;
                }
            }
        }
    }
}

// ---------------- workspace init ----------------
__global__ void init_ws(float* hbuf, int* flags) {
    int t = blockIdx.x * 256 + threadIdx.x;
    if (t < 4096) hbuf[t] = 0.f;
    if (t < 512) flags[t] = 0;
}

// ---------------- GRU persistent kernel ----------------
// 128 WGs x 256 threads, co-resident. WG wg owns hidden units u0=wg*8 .. u0+7.
// Fully decoupled waves: wave w owns units u0+2w, u0+2w+1 (rows q=g*2+u).
// NO __syncthreads in the step loop. Lanes 0-31 accumulate batch 0,
// lanes 32-63 batch 1 (32 contiguous h floats per lane -> 5-stage reduce).
// Lanes 0/32 do pointwise + publish (dwordx2), wave-wide vmcnt ack, then
// lane 0 stores the per-(WG,wave) flag. Each wave polls all 512 flags
// (2KB) with 2 dwordx4 per lane.
__global__ __launch_bounds__(256, 1) void gru_kernel(
    const float* __restrict__ xp,     // [2048][3072], row = b*1024+t (b_ih added)
    const float* __restrict__ w_hh,   // [3072][1024]
    const float* __restrict__ b_hh,   // [3072]
    float* __restrict__ states,       // [2048][1024]
    float* __restrict__ hbuf,         // 2 parities x [2][1024] floats
    int* __restrict__ flags)          // 512 flags (wg*4+w)
{
    __shared__ unsigned short wlds[24 * 1024];  // bf16 weights, permuted [c][hl][8]

    const int wg = blockIdx.x, tid = threadIdx.x;
    const int u0 = wg * 8;
    const int w = tid >> 6, lane = tid & 63;
    const int half = lane >> 5, hl = lane & 31;

    // stage weights, permuted within each row so ds_read_b128 is stride-16B:
    // in-row bf16 index kk -> physical c*256 + hl*8 + e (kk = hl*32 + c*8 + e)
    for (int idx = tid; idx < 24 * 1024; idx += 256) {
        const int rr = idx >> 10, kk = idx & 1023;
        const int w_ = rr / 6, q = rr - 6 * w_;
        const int g = q >> 1, u = q & 1;
        const int grow = (g << 10) + u0 + 2 * w_ + u;
        const int hl_ = kk >> 5, rem = kk & 31, c_ = rem >> 3, e = rem & 7;
        wlds[(rr << 10) + c_ * 256 + hl_ * 8 + e] =
            f2bf(w_hh[((size_t)grow << 10) | kk]);
    }

    // wave-uniform biases for this wave's two units (adjacent -> float2)
    const int uA = u0 + 2 * w;
    const float2 bhr = *(const float2*)&b_hh[uA];
    const float2 bhz = *(const float2*)&b_hh[1024 + uA];
    const float2 bhn = *(const float2*)&b_hh[2048 + uA];

    __syncthreads();   // weights staged (only barrier in the kernel)

    float hpA = 0.f, hpB = 0.f;

    for (int t = 0; t < 1024; ++t) {
        const int p = t & 1;
        const float* src = hbuf + p * 2048;
        float* dst = hbuf + (1 - p) * 2048;

        // ---- prefetch xp gates for the two pointwise lanes (independent of h) ----
        float2 xr_ = make_float2(0.f, 0.f);
        float2 xz_ = make_float2(0.f, 0.f);
        float2 xn_ = make_float2(0.f, 0.f);
        if (hl == 0) {
            const float* xr = xp + (size_t)((half << 10) | t) * 3072 + uA;
            xr_ = *(const float2*)xr;
            xz_ = *(const float2*)(xr + 1024);
            xn_ = *(const float2*)(xr + 2048);
        }

        // ---- poll all 512 wave-flags (8 per lane, 2 dwordx4) ----
        if (t > 0) {
            const char* fa = (const char*)flags + (lane << 5);
            const int need = t;
            i32x4 f0, f1;
            for (;;) {
                asm volatile(
                    "global_load_dwordx4 %0, %2, off sc0 sc1\n\t"
                    "global_load_dwordx4 %1, %2, off offset:16 sc0 sc1\n\t"
                    "s_waitcnt vmcnt(0)"
                    : "=&v"(f0), "=&v"(f1) : "v"(fa) : "memory");
                int m = f0.x < f0.y ? f0.x : f0.y;
                m = m < f0.z ? m : f0.z;  m = m < f0.w ? m : f0.w;
                m = m < f1.x ? m : f1.x;  m = m < f1.y ? m : f1.y;
                m = m < f1.z ? m : f1.z;  m = m < f1.w ? m : f1.w;
                if (__all(m >= need)) break;
            }
        }

        // ---- load this lane's 32 h floats (batch = half) from MALL ----
        f32x4 h_[8];
        {
            const char* hb = (const char*)src + (half << 12) + (hl << 7);
            asm volatile(
                "global_load_dwordx4 %0, %8, off sc0 sc1\n\t"
                "global_load_dwordx4 %1, %8, off offset:16 sc0 sc1\n\t"
                "global_load_dwordx4 %2, %8, off offset:32 sc0 sc1\n\t"
                "global_load_dwordx4 %3, %8, off offset:48 sc0 sc1\n\t"
                "global_load_dwordx4 %4, %8, off offset:64 sc0 sc1\n\t"
                "global_load_dwordx4 %5, %8, off offset:80 sc0 sc1\n\t"
                "global_load_dwordx4 %6, %8, off offset:96 sc0 sc1\n\t"
                "global_load_dwordx4 %7, %8, off offset:112 sc0 sc1\n\t"
                "s_waitcnt vmcnt(0)"
                : "=&v"(h_[0]), "=&v"(h_[1]), "=&v"(h_[2]), "=&v"(h_[3]),
                  "=&v"(h_[4]), "=&v"(h_[5]), "=&v"(h_[6]), "=&v"(h_[7])
                : "v"(hb)
                : "memory");
        }

        // ---- 6 rows (q = g*2+u): partial dot over this lane's 32 h ----
        float pacc[6];
        #pragma unroll
        for (int q = 0; q < 6; ++q) {
            const uint4* wr4 = (const uint4*)&wlds[(w * 6 + q) << 10];
            float a = 0.f;
            #pragma unroll
            for (int c = 0; c < 4; ++c) {
                const uint4 wv = wr4[c * 32 + hl];
                const f32x4 ha = h_[c * 2], hb2 = h_[c * 2 + 1];
                a += bf_lo(wv.x) * ha.x  + bf_hi(wv.x) * ha.y
                   + bf_lo(wv.y) * ha.z  + bf_hi(wv.y) * ha.w
                   + bf_lo(wv.z) * hb2.x + bf_hi(wv.z) * hb2.y
                   + bf_lo(wv.w) * hb2.z + bf_hi(wv.w) * hb2.w;
            }
            pacc[q] = a;
        }
        // 5-stage butterfly within each 32-lane half
        #pragma unroll
        for (int off = 16; off > 0; off >>= 1) {
            #pragma unroll
            for (int q = 0; q < 6; ++q)
                pacc[q] += __shfl_xor(pacc[q], off);
        }

        // ---- pointwise + publish: lane 0 (batch 0) and lane 32 (batch 1) ----
        if (hl == 0) {
            const float rA = 1.f / (1.f + __expf(-(xr_.x + pacc[0] + bhr.x)));
            const float zA = 1.f / (1.f + __expf(-(xz_.x + pacc[2] + bhz.x)));
            const float nA = tanhf(xn_.x + rA * (pacc[4] + bhn.x));
            const float hA = (1.f - zA) * nA + zA * hpA;
            hpA = hA;
            const float rB = 1.f / (1.f + __expf(-(xr_.y + pacc[1] + bhr.y)));
            const float zB = 1.f / (1.f + __expf(-(xz_.y + pacc[3] + bhz.y)));
            const float nB = tanhf(xn_.y + rB * (pacc[5] + bhn.y));
            const float hB = (1.f - zB) * nB + zB * hpB;
            hpB = hB;

            *(float2*)&states[(size_t)((half << 10) | t) * 1024 + uA] =
                make_float2(hA, hB);

            float2 hv = make_float2(hA, hB);
            float* daddr = dst + (half << 10) + uA;
            asm volatile("global_store_dwordx2 %0, %1, off sc0 sc1"
                         :: "v"(daddr), "v"(hv) : "memory");
        }
        asm volatile("s_waitcnt vmcnt(0)" ::: "memory");   // wave-wide ack
        if (lane == 0) {
            int* faddr = flags + (wg << 2) + w;
            const int tv = t + 1;
            asm volatile("global_store_dword %0, %1, off sc0 sc1"
                         :: "v"(faddr), "v"(tv) : "memory");
        }
        // no barrier: each wave loops independently
    }
}

// ---------------- gate = sigmoid(states @ Wg^T + bg), one wave per row ----------------
__global__ __launch_bounds__(256) void gate_kernel(
    const float* __restrict__ states, const float* __restrict__ Wg,
    const float* __restrict__ bg, float* __restrict__ gate)
{
    const int w = threadIdx.x >> 6, lane = threadIdx.x & 63;
    const int row = blockIdx.x * 4 + w;
    const float4* sr = (const float4*)(states + (size_t)row * 1024);
    const float4* wr = (const float4*)Wg;
    float p = 0.f;
    for (int c = 0; c < 4; ++c) {
        const float4 sv = sr[c * 64 + lane];
        const float4 wv = wr[c * 64 + lane];
        p += sv.x * wv.x + sv.y * wv.y + sv.z * wv.z + sv.w * wv.w;
    }
    for (int off = 32; off > 0; off >>= 1) p += __shfl_xor(p, off);
    if (lane == 0) gate[row] = 1.f / (1.f + __expf(-(p + bg[0])));
}

// ---------------- combined = base + gate * residual ----------------
__global__ __launch_bounds__(256) void combined_kernel(
    const float* __restrict__ base, const float* __restrict__ resid,
    const float* __restrict__ gate, float* __restrict__ comb)
{
    const int idx = blockIdx.x * 256 + threadIdx.x;
    const int row = idx >> 9;
    comb[idx] = base[idx] + gate[row] * resid[idx];
}

// ---------------- attention + scatter into logits ----------------
__global__ __launch_bounds__(256) void attn_scatter(
    const float* __restrict__ q,      // [2048][256]
    const float* __restrict__ kT,     // [2][256][1024]
    const float* __restrict__ gate,   // [2048]
    const float* __restrict__ mscale, // [1]
    const int* __restrict__ ids,      // [2][1024]
    float* __restrict__ out)          // [2][1024][32000]
{
    const int i = blockIdx.x, b = blockIdx.y, t = threadIdx.x;
    if (i == 0) return;
    __shared__ float qs[256];
    __shared__ float red[256];

    qs[t] = q[((size_t)((b << 10) | i)) * 256 + t];
    __syncthreads();

    const int j0 = t * 4;
    float s[4] = {0.f, 0.f, 0.f, 0.f};
    const float* kb = kT + (size_t)b * 256 * 1024;
    if (j0 < i) {
        for (int kk = 0; kk < 256; ++kk) {
            const float qv = qs[kk];
            const float4 kv = *(const float4*)(kb + (size_t)kk * 1024 + j0);
            s[0] += qv * kv.x; s[1] += qv * kv.y; s[2] += qv * kv.z; s[3] += qv * kv.w;
        }
    }
    const float scale = 0.0625f;  // 1/sqrt(256)
    float mx = -1e30f;
    for (int e = 0; e < 4; ++e)
        if (j0 + e < i) { s[e] *= scale; mx = fmaxf(mx, s[e]); }

    red[t] = mx; __syncthreads();
    for (int o = 128; o > 0; o >>= 1) {
        if (t < o) red[t] = fmaxf(red[t], red[t + o]);
        __syncthreads();
    }
    const float m = red[0];
    __syncthreads();

    float p[4]; float ssum = 0.f;
    for (int e = 0; e < 4; ++e) {
        if (j0 + e < i) { p[e] = __expf(s[e] - m); ssum += p[e]; }
        else p[e] = 0.f;
    }
    red[t] = ssum; __syncthreads();
    for (int o = 128; o > 0; o >>= 1) {
        if (t < o) red[t] += red[t + o];
        __syncthreads();
    }
    const float denom = fmaxf(red[0], 1e-6f);
    const float g6 = gate[(b << 10) | i] * mscale[0] / denom;

    float* orow = out + ((size_t)((b << 10) | i)) * 32000;
    const int* idr = ids + (b << 10);
    for (int e = 0; e < 4; ++e)
        if (j0 + e < i) atomicAdd(&orow[idr[j0 + e]], p[e] * g6);
}

// ---------------- launch ----------------
extern "C" void kernel_launch(void* const* d_in, const int* in_sizes, int n_in,
                              void* d_out, int out_size, void* d_ws, size_t ws_size,
                              hipStream_t stream)
{
    const int*   ids     = (const int*)  d_in[0];
    const float* emb_W   = (const float*)d_in[1];
    const float* w_ih    = (const float*)d_in[2];
    const float* w_hh    = (const float*)d_in[3];
    const float* b_ih    = (const float*)d_in[4];
    const float* b_hh    = (const float*)d_in[5];
    const float* Wq      = (const float*)d_in[6];
    const float* bq      = (const float*)d_in[7];
    const float* Wk      = (const float*)d_in[8];
    const float* bk      = (const float*)d_in[9];
    const float* Wg      = (const float*)d_in[10];
    const float* bg      = (const float*)d_in[11];
    const float* W1      = (const float*)d_in[12];
    const float* b1      = (const float*)d_in[13];
    const float* W2      = (const float*)d_in[14];
    const float* b2      = (const float*)d_in[15];
    const float* Wr      = (const float*)d_in[16];
    const float* br      = (const float*)d_in[17];
    const float* mscale  = (const float*)d_in[18];
    const float* out_b   = (const float*)d_in[19];
    float* out = (float*)d_out;

    float* ws = (float*)d_ws;
    float* xp     = ws;                         // 2048*3072
    float* states = xp     + (size_t)2048 * 3072;
    float* hf     = states + (size_t)2048 * 1024;
    float* base   = hf     + (size_t)2048 * 2048;
    float* resid  = base   + (size_t)2048 * 512;
    float* qv     = resid  + (size_t)2048 * 512;
    float* kT     = qv     + (size_t)2048 * 256;
    float* comb   = kT     + (size_t)2 * 256 * 1024;
    float* gate   = comb   + (size_t)2048 * 512;
    float* hbuf   = gate   + 2048;              // 4096 floats (2 parities)
    int*   flags  = (int*)(hbuf + 4096);        // 512 ints

    dim3 blk(256);

    gemm_bt<ACT_NONE, true, false><<<dim3(32, 48), blk, 0, stream>>>(
        emb_W, w_ih, b_ih, xp, ids, 2048, 3072, 512);

    init_ws<<<16, blk, 0, stream>>>(hbuf, flags);
    gru_kernel<<<128, blk, 0, stream>>>(xp, w_hh, b_hh, states, hbuf, flags);

    gemm_bt<ACT_RELU2, false, false><<<dim3(32, 32), blk, 0, stream>>>(
        states, W1, b1, hf, nullptr, 2048, 2048, 1024);

    gemm_bt<ACT_NONE, false, false><<<dim3(32, 8), blk, 0, stream>>>(
        hf, W2, b2, base, nullptr, 2048, 512, 2048);

    gemm_bt<ACT_RELU, false, false><<<dim3(32, 8), blk, 0, stream>>>(
        base, Wr, br, resid, nullptr, 2048, 512, 512);

    gate_kernel<<<512, blk, 0, stream>>>(states, Wg, bg, gate);

    gemm_bt<ACT_NONE, false, false><<<dim3(32, 4), blk, 0, stream>>>(
        states, Wq, bq, qv, nullptr, 2048, 256, 1024);
    gemm_bt<ACT_NONE, false, true><<<dim3(32, 4), blk, 0, stream>>>(
        states, Wk, bk, kT, nullptr, 2048, 256, 1024);

    combined_kernel<<<4096, blk, 0, stream>>>(base, resid, gate, comb);

    gemm_bt<ACT_NONE, false, false><<<dim3(32, 500), blk, 0, stream>>>(
        comb, emb_W, out_b, out, nullptr, 2048, 32000, 512);

    attn_scatter<<<dim3(1024, 2), blk, 0, stream>>>(qv, kT, gate, mscale, ids, out);
}

// Round 4
// 5965.882 us; speedup vs baseline: 1.3407x; 1.3407x over previous
//
#include <hip/hip_runtime.h>
#include <math.h>

// ---------------- common types ----------------
typedef __attribute__((ext_vector_type(8))) short bf16x8;
typedef __attribute__((ext_vector_type(4))) float f32x4;
typedef __attribute__((ext_vector_type(4))) int i32x4;

__device__ __forceinline__ unsigned short f2bf(float x) {
    unsigned u = __float_as_uint(x);
    unsigned r = (u + 0x7FFF + ((u >> 16) & 1)) >> 16;
    return (unsigned short)r;
}

#define ACT_NONE  0
#define ACT_RELU  1
#define ACT_RELU2 2

// ---------------- MFMA GEMM: C[M,N] = act(A[M,K] @ B[N,K]^T + bias[N]) ----------------
// 64x64 tile, BK=32, 256 threads (4 waves, each 32x32 via 2x2 of 16x16x32 mfma).
template <int ACT, bool GATHER, bool TRANSOUT>
__global__ __launch_bounds__(256) void gemm_bt(
    const float* __restrict__ A, const float* __restrict__ Bm,
    const float* __restrict__ bias, float* __restrict__ C,
    const int* __restrict__ ids, int M, int N, int K)
{
    __shared__ unsigned short as_[64][40];
    __shared__ unsigned short bs_[64][40];

    const int tid = threadIdx.x;
    const int bm = blockIdx.x, bn = blockIdx.y;
    const int r = tid >> 2, seg = tid & 3;

    const int arow = bm * 64 + r;
    const float* aptr = GATHER ? (A + (size_t)ids[arow] * K) : (A + (size_t)arow * K);
    const float* bptr = Bm + (size_t)(bn * 64 + r) * K;

    const int w = tid >> 6, lane = tid & 63;
    const int wr = w >> 1, wc = w & 1;
    const int al = lane & 15, kq = lane >> 4;

    f32x4 acc[2][2];
    for (int mi = 0; mi < 2; ++mi)
        for (int ni = 0; ni < 2; ++ni)
            acc[mi][ni] = (f32x4){0.f, 0.f, 0.f, 0.f};

    for (int k0 = 0; k0 < K; k0 += 32) {
        __syncthreads();
        {
            const float4* ap4 = (const float4*)(aptr + k0 + seg * 8);
            float4 a0 = ap4[0], a1 = ap4[1];
            uint4 pk;
            pk.x = (unsigned)f2bf(a0.x) | ((unsigned)f2bf(a0.y) << 16);
            pk.y = (unsigned)f2bf(a0.z) | ((unsigned)f2bf(a0.w) << 16);
            pk.z = (unsigned)f2bf(a1.x) | ((unsigned)f2bf(a1.y) << 16);
            pk.w = (unsigned)f2bf(a1.z) | ((unsigned)f2bf(a1.w) << 16);
            *(uint4*)&as_[r][seg * 8] = pk;

            const float4* bp4 = (const float4*)(bptr + k0 + seg * 8);
            float4 b0 = bp4[0], b1 = bp4[1];
            pk.x = (unsigned)f2bf(b0.x) | ((unsigned)f2bf(b0.y) << 16);
            pk.y = (unsigned)f2bf(b0.z) | ((unsigned)f2bf(b0.w) << 16);
            pk.z = (unsigned)f2bf(b1.x) | ((unsigned)f2bf(b1.y) << 16);
            pk.w = (unsigned)f2bf(b1.z) | ((unsigned)f2bf(b1.w) << 16);
            *(uint4*)&bs_[r][seg * 8] = pk;
        }
        __syncthreads();

        bf16x8 af[2], bfr[2];
        af[0]  = *(const bf16x8*)&as_[wr * 32 + al][kq * 8];
        af[1]  = *(const bf16x8*)&as_[wr * 32 + 16 + al][kq * 8];
        bfr[0] = *(const bf16x8*)&bs_[wc * 32 + al][kq * 8];
        bfr[1] = *(const bf16x8*)&bs_[wc * 32 + 16 + al][kq * 8];

        for (int mi = 0; mi < 2; ++mi)
            for (int ni = 0; ni < 2; ++ni)
                acc[mi][ni] = __builtin_amdgcn_mfma_f32_16x16x32_bf16(
                    af[mi], bfr[ni], acc[mi][ni], 0, 0, 0);
    }

    for (int mi = 0; mi < 2; ++mi) {
        for (int ni = 0; ni < 2; ++ni) {
            const int gcol = bn * 64 + wc * 32 + ni * 16 + al;
            const float bv = bias ? bias[gcol] : 0.f;
            for (int i = 0; i < 4; ++i) {
                const int grow = bm * 64 + wr * 32 + mi * 16 + kq * 4 + i;
                float v = acc[mi][ni][i] + bv;
                if (ACT == ACT_RELU)  v = fmaxf(v, 0.f);
                if (ACT == ACT_RELU2) { v = fmaxf(v, 0.f); v = v * v; }
                if (TRANSOUT) {
                    const int b = grow >> 10, s = grow & 1023;
                    C[((size_t)b * N + gcol) * 1024 + s] = v;
                } else {
                    C[(size_t)grow * N + gcol] = v;
                }
            }
        }
    }
}

// ---------------- workspace init ----------------
__global__ void init_ws(float* hbuf) {
    int t = blockIdx.x * 256 + threadIdx.x;
    if (t < 8192) hbuf[t] = 0.f;   // both slots: h=0, tag=0
}

// ---------------- GRU persistent kernel ----------------
// 128 WGs x 256 threads, co-resident. WG wg owns hidden units u0=wg*8..u0+7;
// wave w owns units uA=u0+2w, uA+1 for BOTH batches.
// Self-validating records: record r (= b*1024+u, u even pairs) is 16B
// {h_u, tag, h_u+1, tag} published by ONE global_store_dwordx4 sc0 sc1 ->
// tag+data visible atomically: no ack, no flag, and the consumers' poll
// loads ARE the data loads (detection == arrival). Each wave polls only
// its quarter (4 dwordx4/lane = 4KB/sweep), writes it to LDS, ONE barrier
// broadcasts h. Parity double-buffer; tag == t exact match (producer can
// never be 2 steps ahead: its own barrier gates on everyone's tag-t).
__global__ __launch_bounds__(256, 1) void gru_kernel(
    const float* __restrict__ xp,     // [2048][3072], row = b*1024+t (b_ih added)
    const float* __restrict__ w_hh,   // [3072][1024]
    const float* __restrict__ b_hh,   // [3072]
    float* __restrict__ states,       // [2048][1024]
    float* __restrict__ hbuf)         // 2 slots x 2048 records x 8B
{
    __shared__ float wlds[24][1024];  // f32 weights, 96KB
    __shared__ float hs_[2][1024];    // h broadcast, 8KB

    const int wg = blockIdx.x, tid = threadIdx.x;
    const int u0 = wg * 8;
    const int w = tid >> 6, lane = tid & 63;
    const int half = lane >> 5, hl = lane & 31;

    // stage f32 weights: row rr = w_*6 + g*2 + u  (gate g, unit u of wave w_)
    for (int idx = tid; idx < 24 * 1024; idx += 256) {
        const int rr = idx >> 10, k = idx & 1023;
        const int w_ = rr / 6, rem = rr - 6 * w_;
        const int g = rem >> 1, u = rem & 1;
        const int grow = (g << 10) + u0 + 2 * w_ + u;
        wlds[rr][k] = w_hh[((size_t)grow << 10) | k];
    }

    const int uA = u0 + 2 * w;
    const float2 bhr = *(const float2*)&b_hh[uA];
    const float2 bhz = *(const float2*)&b_hh[1024 + uA];
    const float2 bhn = *(const float2*)&b_hh[2048 + uA];

    __syncthreads();

    float hpA = 0.f, hpB = 0.f;   // live on lanes 0 (batch0) / 32 (batch1)

    for (int t = 0; t < 1024; ++t) {
        const char* slotR = (const char*)hbuf + (t & 1) * 16384;
        char* slotW = (char*)hbuf + ((t + 1) & 1) * 16384;

        // ---- xp gate prefetch for pointwise lanes (independent of h) ----
        float2 xr_ = make_float2(0.f, 0.f);
        float2 xz_ = make_float2(0.f, 0.f);
        float2 xn_ = make_float2(0.f, 0.f);
        if (hl == 0) {
            const float* xr = xp + (size_t)((half << 10) | t) * 3072 + uA;
            xr_ = *(const float2*)xr;
            xz_ = *(const float2*)(xr + 1024);
            xn_ = *(const float2*)(xr + 2048);
        }

        // ---- poll this wave's quarter: records r in [w*512, w*512+512) ----
        // lane covers r = w*512 + jj*128 + lane*2 (+1), jj=0..3: 4 dwordx4.
        i32x4 pq[4];
        {
            const char* pbase = slotR + (w << 12) + (lane << 4);
            const int expect = t;
            for (;;) {
                asm volatile(
                    "global_load_dwordx4 %0, %4, off sc0 sc1\n\t"
                    "global_load_dwordx4 %1, %4, off offset:1024 sc0 sc1\n\t"
                    "global_load_dwordx4 %2, %4, off offset:2048 sc0 sc1\n\t"
                    "global_load_dwordx4 %3, %4, off offset:3072 sc0 sc1\n\t"
                    "s_waitcnt vmcnt(0)"
                    : "=&v"(pq[0]), "=&v"(pq[1]), "=&v"(pq[2]), "=&v"(pq[3])
                    : "v"(pbase) : "memory");
                bool ok = true;
                #pragma unroll
                for (int k = 0; k < 4; ++k)
                    ok = ok && (pq[k].y == expect) && (pq[k].w == expect);
                if (__all(ok)) break;
            }
        }
        // ---- write quarter to LDS ----
        #pragma unroll
        for (int jj = 0; jj < 4; ++jj) {
            const int r = (w << 9) + (jj << 7) + (lane << 1);
            const int b = r >> 10, u = r & 1023;
            *(float2*)&hs_[b][u] =
                make_float2(__int_as_float(pq[jj].x), __int_as_float(pq[jj].z));
        }
        __syncthreads();   // the ONLY barrier per step

        // ---- 12 dots: rows q=0..5 (g*2+u) x batches, full-wave k-slices ----
        // lane k-slice: 4 consecutive floats at c*256 + lane*4 (conflict-free).
        float acc[12];
        #pragma unroll
        for (int i = 0; i < 12; ++i) acc[i] = 0.f;
        #pragma unroll
        for (int c = 0; c < 4; ++c) {
            const int ko = c * 256 + lane * 4;
            const f32x4 h0 = *(const f32x4*)&hs_[0][ko];
            const f32x4 h1 = *(const f32x4*)&hs_[1][ko];
            #pragma unroll
            for (int q = 0; q < 6; ++q) {
                const f32x4 wv = *(const f32x4*)&wlds[w * 6 + q][ko];
                acc[2 * q]     += wv.x * h0.x + wv.y * h0.y + wv.z * h0.z + wv.w * h0.w;
                acc[2 * q + 1] += wv.x * h1.x + wv.y * h1.y + wv.z * h1.z + wv.w * h1.w;
            }
        }
        #pragma unroll
        for (int off = 32; off > 0; off >>= 1) {
            #pragma unroll
            for (int i = 0; i < 12; ++i)
                acc[i] += __shfl_xor(acc[i], off);
        }

        // ---- pointwise + single-store publish: lane 0 (b0), lane 32 (b1) ----
        if (hl == 0) {
            const int b = half;
            const float rA = 1.f / (1.f + __expf(-(xr_.x + acc[0 + b] + bhr.x)));
            const float zA = 1.f / (1.f + __expf(-(xz_.x + acc[4 + b] + bhz.x)));
            const float nA = tanhf(xn_.x + rA * (acc[8 + b] + bhn.x));
            const float hA = (1.f - zA) * nA + zA * hpA;
            hpA = hA;
            const float rB = 1.f / (1.f + __expf(-(xr_.y + acc[2 + b] + bhr.y)));
            const float zB = 1.f / (1.f + __expf(-(xz_.y + acc[6 + b] + bhz.y)));
            const float nB = tanhf(xn_.y + rB * (acc[10 + b] + bhn.y));
            const float hB = (1.f - zB) * nB + zB * hpB;
            hpB = hB;

            *(float2*)&states[(size_t)((b << 10) | t) * 1024 + uA] =
                make_float2(hA, hB);

            i32x4 rec;
            rec.x = __float_as_int(hA);
            rec.y = t + 1;
            rec.z = __float_as_int(hB);
            rec.w = t + 1;
            char* daddr = slotW + ((size_t)((b << 10) + uA) << 3);
            asm volatile("global_store_dwordx4 %0, %1, off sc0 sc1"
                         :: "v"(daddr), "v"(rec) : "memory");
        }
        // no ack, no flag: tag travels in the same 16B transaction as h.
    }
}

// ---------------- gate = sigmoid(states @ Wg^T + bg), one wave per row ----------------
__global__ __launch_bounds__(256) void gate_kernel(
    const float* __restrict__ states, const float* __restrict__ Wg,
    const float* __restrict__ bg, float* __restrict__ gate)
{
    const int w = threadIdx.x >> 6, lane = threadIdx.x & 63;
    const int row = blockIdx.x * 4 + w;
    const float4* sr = (const float4*)(states + (size_t)row * 1024);
    const float4* wr = (const float4*)Wg;
    float p = 0.f;
    for (int c = 0; c < 4; ++c) {
        const float4 sv = sr[c * 64 + lane];
        const float4 wv = wr[c * 64 + lane];
        p += sv.x * wv.x + sv.y * wv.y + sv.z * wv.z + sv.w * wv.w;
    }
    for (int off = 32; off > 0; off >>= 1) p += __shfl_xor(p, off);
    if (lane == 0) gate[row] = 1.f / (1.f + __expf(-(p + bg[0])));
}

// ---------------- combined = base + gate * residual ----------------
__global__ __launch_bounds__(256) void combined_kernel(
    const float* __restrict__ base, const float* __restrict__ resid,
    const float* __restrict__ gate, float* __restrict__ comb)
{
    const int idx = blockIdx.x * 256 + threadIdx.x;
    const int row = idx >> 9;
    comb[idx] = base[idx] + gate[row] * resid[idx];
}

// ---------------- attention + scatter into logits ----------------
__global__ __launch_bounds__(256) void attn_scatter(
    const float* __restrict__ q,      // [2048][256]
    const float* __restrict__ kT,     // [2][256][1024]
    const float* __restrict__ gate,   // [2048]
    const float* __restrict__ mscale, // [1]
    const int* __restrict__ ids,      // [2][1024]
    float* __restrict__ out)          // [2][1024][32000]
{
    const int i = blockIdx.x, b = blockIdx.y, t = threadIdx.x;
    if (i == 0) return;
    __shared__ float qs[256];
    __shared__ float red[256];

    qs[t] = q[((size_t)((b << 10) | i)) * 256 + t];
    __syncthreads();

    const int j0 = t * 4;
    float s[4] = {0.f, 0.f, 0.f, 0.f};
    const float* kb = kT + (size_t)b * 256 * 1024;
    if (j0 < i) {
        for (int kk = 0; kk < 256; ++kk) {
            const float qv = qs[kk];
            const float4 kv = *(const float4*)(kb + (size_t)kk * 1024 + j0);
            s[0] += qv * kv.x; s[1] += qv * kv.y; s[2] += qv * kv.z; s[3] += qv * kv.w;
        }
    }
    const float scale = 0.0625f;  // 1/sqrt(256)
    float mx = -1e30f;
    for (int e = 0; e < 4; ++e)
        if (j0 + e < i) { s[e] *= scale; mx = fmaxf(mx, s[e]); }

    red[t] = mx; __syncthreads();
    for (int o = 128; o > 0; o >>= 1) {
        if (t < o) red[t] = fmaxf(red[t], red[t + o]);
        __syncthreads();
    }
    const float m = red[0];
    __syncthreads();

    float p[4]; float ssum = 0.f;
    for (int e = 0; e < 4; ++e) {
        if (j0 + e < i) { p[e] = __expf(s[e] - m); ssum += p[e]; }
        else p[e] = 0.f;
    }
    red[t] = ssum; __syncthreads();
    for (int o = 128; o > 0; o >>= 1) {
        if (t < o) red[t] += red[t + o];
        __syncthreads();
    }
    const float denom = fmaxf(red[0], 1e-6f);
    const float g6 = gate[(b << 10) | i] * mscale[0] / denom;

    float* orow = out + ((size_t)((b << 10) | i)) * 32000;
    const int* idr = ids + (b << 10);
    for (int e = 0; e < 4; ++e)
        if (j0 + e < i) atomicAdd(&orow[idr[j0 + e]], p[e] * g6);
}

// ---------------- launch ----------------
extern "C" void kernel_launch(void* const* d_in, const int* in_sizes, int n_in,
                              void* d_out, int out_size, void* d_ws, size_t ws_size,
                              hipStream_t stream)
{
    const int*   ids     = (const int*)  d_in[0];
    const float* emb_W   = (const float*)d_in[1];
    const float* w_ih    = (const float*)d_in[2];
    const float* w_hh    = (const float*)d_in[3];
    const float* b_ih    = (const float*)d_in[4];
    const float* b_hh    = (const float*)d_in[5];
    const float* Wq      = (const float*)d_in[6];
    const float* bq      = (const float*)d_in[7];
    const float* Wk      = (const float*)d_in[8];
    const float* bk      = (const float*)d_in[9];
    const float* Wg      = (const float*)d_in[10];
    const float* bg      = (const float*)d_in[11];
    const float* W1      = (const float*)d_in[12];
    const float* b1      = (const float*)d_in[13];
    const float* W2      = (const float*)d_in[14];
    const float* b2      = (const float*)d_in[15];
    const float* Wr      = (const float*)d_in[16];
    const float* br      = (const float*)d_in[17];
    const float* mscale  = (const float*)d_in[18];
    const float* out_b   = (const float*)d_in[19];
    float* out = (float*)d_out;

    float* ws = (float*)d_ws;
    float* xp     = ws;                         // 2048*3072
    float* states = xp     + (size_t)2048 * 3072;
    float* hf     = states + (size_t)2048 * 1024;
    float* base   = hf     + (size_t)2048 * 2048;
    float* resid  = base   + (size_t)2048 * 512;
    float* qv     = resid  + (size_t)2048 * 512;
    float* kT     = qv     + (size_t)2048 * 256;
    float* comb   = kT     + (size_t)2 * 256 * 1024;
    float* gate   = comb   + (size_t)2048 * 512;
    float* hbuf   = gate   + 2048;              // 8192 floats: 2 slots x 2048 x 8B

    dim3 blk(256);

    gemm_bt<ACT_NONE, true, false><<<dim3(32, 48), blk, 0, stream>>>(
        emb_W, w_ih, b_ih, xp, ids, 2048, 3072, 512);

    init_ws<<<32, blk, 0, stream>>>(hbuf);
    gru_kernel<<<128, blk, 0, stream>>>(xp, w_hh, b_hh, states, hbuf);

    gemm_bt<ACT_RELU2, false, false><<<dim3(32, 32), blk, 0, stream>>>(
        states, W1, b1, hf, nullptr, 2048, 2048, 1024);

    gemm_bt<ACT_NONE, false, false><<<dim3(32, 8), blk, 0, stream>>>(
        hf, W2, b2, base, nullptr, 2048, 512, 2048);

    gemm_bt<ACT_RELU, false, false><<<dim3(32, 8), blk, 0, stream>>>(
        base, Wr, br, resid, nullptr, 2048, 512, 512);

    gate_kernel<<<512, blk, 0, stream>>>(states, Wg, bg, gate);

    gemm_bt<ACT_NONE, false, false><<<dim3(32, 4), blk, 0, stream>>>(
        states, Wq, bq, qv, nullptr, 2048, 256, 1024);
    gemm_bt<ACT_NONE, false, true><<<dim3(32, 4), blk, 0, stream>>>(
        states, Wk, bk, kT, nullptr, 2048, 256, 1024);

    combined_kernel<<<4096, blk, 0, stream>>>(base, resid, gate, comb);

    gemm_bt<ACT_NONE, false, false><<<dim3(32, 500), blk, 0, stream>>>(
        comb, emb_W, out_b, out, nullptr, 2048, 32000, 512);

    attn_scatter<<<dim3(1024, 2), blk, 0, stream>>>(qv, kT, gate, mscale, ids, out);
}

// Round 5
// 5031.994 us; speedup vs baseline: 1.5895x; 1.1856x over previous
//
#include <hip/hip_runtime.h>
#include <math.h>

// ---------------- common types ----------------
typedef __attribute__((ext_vector_type(8))) short bf16x8;
typedef __attribute__((ext_vector_type(4))) float f32x4;

__device__ __forceinline__ unsigned short f2bf(float x) {
    unsigned u = __float_as_uint(x);
    unsigned r = (u + 0x7FFF + ((u >> 16) & 1)) >> 16;
    return (unsigned short)r;
}
__device__ __forceinline__ float bf_lo(unsigned u) { return __uint_as_float(u << 16); }
__device__ __forceinline__ float bf_hi(unsigned u) { return __uint_as_float(u & 0xffff0000u); }

#define ACT_NONE  0
#define ACT_RELU  1
#define ACT_RELU2 2

// ---------------- MFMA GEMM: C[M,N] = act(A[M,K] @ B[N,K]^T + bias[N]) ----------------
// 64x64 tile, BK=32, 256 threads (4 waves, each 32x32 via 2x2 of 16x16x32 mfma).
template <int ACT, bool GATHER, bool TRANSOUT>
__global__ __launch_bounds__(256) void gemm_bt(
    const float* __restrict__ A, const float* __restrict__ Bm,
    const float* __restrict__ bias, float* __restrict__ C,
    const int* __restrict__ ids, int M, int N, int K)
{
    __shared__ unsigned short as_[64][40];
    __shared__ unsigned short bs_[64][40];

    const int tid = threadIdx.x;
    const int bm = blockIdx.x, bn = blockIdx.y;
    const int r = tid >> 2, seg = tid & 3;

    const int arow = bm * 64 + r;
    const float* aptr = GATHER ? (A + (size_t)ids[arow] * K) : (A + (size_t)arow * K);
    const float* bptr = Bm + (size_t)(bn * 64 + r) * K;

    const int w = tid >> 6, lane = tid & 63;
    const int wr = w >> 1, wc = w & 1;
    const int al = lane & 15, kq = lane >> 4;

    f32x4 acc[2][2];
    for (int mi = 0; mi < 2; ++mi)
        for (int ni = 0; ni < 2; ++ni)
            acc[mi][ni] = (f32x4){0.f, 0.f, 0.f, 0.f};

    for (int k0 = 0; k0 < K; k0 += 32) {
        __syncthreads();
        {
            const float4* ap4 = (const float4*)(aptr + k0 + seg * 8);
            float4 a0 = ap4[0], a1 = ap4[1];
            uint4 pk;
            pk.x = (unsigned)f2bf(a0.x) | ((unsigned)f2bf(a0.y) << 16);
            pk.y = (unsigned)f2bf(a0.z) | ((unsigned)f2bf(a0.w) << 16);
            pk.z = (unsigned)f2bf(a1.x) | ((unsigned)f2bf(a1.y) << 16);
            pk.w = (unsigned)f2bf(a1.z) | ((unsigned)f2bf(a1.w) << 16);
            *(uint4*)&as_[r][seg * 8] = pk;

            const float4* bp4 = (const float4*)(bptr + k0 + seg * 8);
            float4 b0 = bp4[0], b1 = bp4[1];
            pk.x = (unsigned)f2bf(b0.x) | ((unsigned)f2bf(b0.y) << 16);
            pk.y = (unsigned)f2bf(b0.z) | ((unsigned)f2bf(b0.w) << 16);
            pk.z = (unsigned)f2bf(b1.x) | ((unsigned)f2bf(b1.y) << 16);
            pk.w = (unsigned)f2bf(b1.z) | ((unsigned)f2bf(b1.w) << 16);
            *(uint4*)&bs_[r][seg * 8] = pk;
        }
        __syncthreads();

        bf16x8 af[2], bfr[2];
        af[0]  = *(const bf16x8*)&as_[wr * 32 + al][kq * 8];
        af[1]  = *(const bf16x8*)&as_[wr * 32 + 16 + al][kq * 8];
        bfr[0] = *(const bf16x8*)&bs_[wc * 32 + al][kq * 8];
        bfr[1] = *(const bf16x8*)&bs_[wc * 32 + 16 + al][kq * 8];

        for (int mi = 0; mi < 2; ++mi)
            for (int ni = 0; ni < 2; ++ni)
                acc[mi][ni] = __builtin_amdgcn_mfma_f32_16x16x32_bf16(
                    af[mi], bfr[ni], acc[mi][ni], 0, 0, 0);
    }

    for (int mi = 0; mi < 2; ++mi) {
        for (int ni = 0; ni < 2; ++ni) {
            const int gcol = bn * 64 + wc * 32 + ni * 16 + al;
            const float bv = bias ? bias[gcol] : 0.f;
            for (int i = 0; i < 4; ++i) {
                const int grow = bm * 64 + wr * 32 + mi * 16 + kq * 4 + i;
                float v = acc[mi][ni][i] + bv;
                if (ACT == ACT_RELU)  v = fmaxf(v, 0.f);
                if (ACT == ACT_RELU2) { v = fmaxf(v, 0.f); v = v * v; }
                if (TRANSOUT) {
                    const int b = grow >> 10, s = grow & 1023;
                    C[((size_t)b * N + gcol) * 1024 + s] = v;
                } else {
                    C[(size_t)grow * N + gcol] = v;
                }
            }
        }
    }
}

// ---------------- workspace init ----------------
__global__ void init_ws(float* hbuf2, int* flags) {
    int t = blockIdx.x * 256 + threadIdx.x;
    if (t < 8192) hbuf2[t] = 0.f;   // both slots: h=0, tag=0
    if (t < 4096) flags[t] = 0;
}

// ---------------- GRU persistent kernel ----------------
// 128 WGs x 256 threads, co-resident. WG wg owns hidden units u0=wg*8 .. u0+7.
// Protocol = round-1 skeleton (verified 3357us) minus the producer ack RT:
//  - h published as tagged 8B records {h, step_tag} via global_store_dwordx2
//    sc0 sc1; the per-WG flag store issues IMMEDIATELY after (no vmcnt ack).
//  - consumers poll the tiny padded flag array (wave 0 only, scalar atomic
//    loads -- identical to round 1), then load tagged h and VALIDATE
//    tag == t, retrying if the flag outran the data (rare).
//  - everything else (weights in bf16 LDS, dot, two barriers, ghs) = round 1.
__global__ __launch_bounds__(256, 1) void gru_kernel(
    const float* __restrict__ xp,     // [2048][3072], row = b*1024+t (b_ih added)
    const float* __restrict__ w_hh,   // [3072][1024]
    const float* __restrict__ b_hh,   // [3072]
    float* __restrict__ states,       // [2048][1024]
    float* __restrict__ hbuf2,        // 2 slots x 2048 records x 8B {h, tag}
    int* __restrict__ flags)          // 128 flags, padded stride 32 ints
{
    __shared__ unsigned short wlds[24 * 1024];  // bf16 weights
    __shared__ float ghs[24][2];
    __shared__ float bh[24];

    const int wg = blockIdx.x, tid = threadIdx.x;
    const int u0 = wg * 8;

    for (int idx = tid; idx < 24 * 1024; idx += 256) {
        const int rr = idx >> 10, kk = idx & 1023;
        const int grow = (rr < 8) ? (u0 + rr) : (rr < 16) ? (1024 + u0 + rr - 8) : (2048 + u0 + rr - 16);
        wlds[idx] = f2bf(w_hh[((size_t)grow << 10) | kk]);
    }
    if (tid < 24) {
        const int rr = tid;
        const int grow = (rr < 8) ? (u0 + rr) : (rr < 16) ? (1024 + u0 + rr - 8) : (2048 + u0 + rr - 16);
        bh[rr] = b_hh[grow];
    }
    __syncthreads();

    const int w = tid >> 6, lane = tid & 63;
    const int j = tid & 7, bb = (tid >> 3) & 1;          // pointwise mapping (tid<16)
    const float* xbase = xp + ((size_t)(bb << 10)) * 3072 + u0 + j;
    float hprev = 0.f;

    for (int t = 0; t < 1024; ++t) {
        const int p = t & 1;
        const char* slotR = (const char*)hbuf2 + p * 16384;
        char* slotW = (char*)hbuf2 + (1 - p) * 16384;

        // ---- prefetch xp gates (independent of h) ----
        float ir = 0.f, iz = 0.f, inn = 0.f;
        if (tid < 16) {
            const float* xr = xbase + (size_t)t * 3072;
            ir = xr[0]; iz = xr[1024]; inn = xr[2048];
        }

        // ---- wave 0: poll all 128 flags (scalar atomic loads, as round 1) ----
        if (w == 0 && t > 0) {
            const int need = t;
            for (;;) {
                int f0 = __hip_atomic_load(&flags[lane << 5],
                                           __ATOMIC_RELAXED, __HIP_MEMORY_SCOPE_AGENT);
                int f1 = __hip_atomic_load(&flags[(64 + lane) << 5],
                                           __ATOMIC_RELAXED, __HIP_MEMORY_SCOPE_AGENT);
                if (__all(f0 >= need && f1 >= need)) break;
            }
        }
        __syncthreads();

        // ---- tagged h load + validate: lane's 32 {h,tag} pairs, one RT ----
        // group (b,c): units c*512 + lane*8 .. +7, bytes b*8192 + c*4096 + lane*64
        f32x4 h_[16];
        {
            const char* g0 = slotR + (lane << 6);   // b0 c0
            const char* g1 = g0 + 4096;             // b0 c1
            const char* g2 = g0 + 8192;             // b1 c0
            const char* g3 = g0 + 12288;            // b1 c1
            const unsigned et = (unsigned)t;
            for (;;) {
                asm volatile(
                    "global_load_dwordx4 %0, %16, off sc0 sc1\n\t"
                    "global_load_dwordx4 %1, %16, off offset:16 sc0 sc1\n\t"
                    "global_load_dwordx4 %2, %16, off offset:32 sc0 sc1\n\t"
                    "global_load_dwordx4 %3, %16, off offset:48 sc0 sc1\n\t"
                    "global_load_dwordx4 %4, %17, off sc0 sc1\n\t"
                    "global_load_dwordx4 %5, %17, off offset:16 sc0 sc1\n\t"
                    "global_load_dwordx4 %6, %17, off offset:32 sc0 sc1\n\t"
                    "global_load_dwordx4 %7, %17, off offset:48 sc0 sc1\n\t"
                    "global_load_dwordx4 %8, %18, off sc0 sc1\n\t"
                    "global_load_dwordx4 %9, %18, off offset:16 sc0 sc1\n\t"
                    "global_load_dwordx4 %10, %18, off offset:32 sc0 sc1\n\t"
                    "global_load_dwordx4 %11, %18, off offset:48 sc0 sc1\n\t"
                    "global_load_dwordx4 %12, %19, off sc0 sc1\n\t"
                    "global_load_dwordx4 %13, %19, off offset:16 sc0 sc1\n\t"
                    "global_load_dwordx4 %14, %19, off offset:32 sc0 sc1\n\t"
                    "global_load_dwordx4 %15, %19, off offset:48 sc0 sc1\n\t"
                    "s_waitcnt vmcnt(0)"
                    : "=&v"(h_[0]), "=&v"(h_[1]), "=&v"(h_[2]), "=&v"(h_[3]),
                      "=&v"(h_[4]), "=&v"(h_[5]), "=&v"(h_[6]), "=&v"(h_[7]),
                      "=&v"(h_[8]), "=&v"(h_[9]), "=&v"(h_[10]), "=&v"(h_[11]),
                      "=&v"(h_[12]), "=&v"(h_[13]), "=&v"(h_[14]), "=&v"(h_[15])
                    : "v"(g0), "v"(g1), "v"(g2), "v"(g3)
                    : "memory");
                bool ok = true;
                #pragma unroll
                for (int k = 0; k < 16; ++k)
                    ok = ok && (__float_as_uint(h_[k].y) == et)
                            && (__float_as_uint(h_[k].w) == et);
                if (__all(ok)) break;   // flag preceded data: retry (rare)
            }
        }

        // ---- 6 rows per wave: accumulate (h at .x/.z), butterfly reduce ----
        float pacc[6][2];
        #pragma unroll
        for (int rr6 = 0; rr6 < 6; ++rr6) {
            pacc[rr6][0] = 0.f; pacc[rr6][1] = 0.f;
            const uint4* wr4 = (const uint4*)&wlds[(w * 6 + rr6) << 10];
            #pragma unroll
            for (int c = 0; c < 2; ++c) {
                const uint4 wv = wr4[c * 64 + lane];
                const float w0 = bf_lo(wv.x), w1 = bf_hi(wv.x);
                const float w2 = bf_lo(wv.y), w3 = bf_hi(wv.y);
                const float w4 = bf_lo(wv.z), w5 = bf_hi(wv.z);
                const float w6 = bf_lo(wv.w), w7 = bf_hi(wv.w);
                const int g = c * 4;
                pacc[rr6][0] += w0 * h_[g].x     + w1 * h_[g].z
                              + w2 * h_[g + 1].x + w3 * h_[g + 1].z
                              + w4 * h_[g + 2].x + w5 * h_[g + 2].z
                              + w6 * h_[g + 3].x + w7 * h_[g + 3].z;
                pacc[rr6][1] += w0 * h_[8 + g].x     + w1 * h_[8 + g].z
                              + w2 * h_[8 + g + 1].x + w3 * h_[8 + g + 1].z
                              + w4 * h_[8 + g + 2].x + w5 * h_[8 + g + 2].z
                              + w6 * h_[8 + g + 3].x + w7 * h_[8 + g + 3].z;
            }
        }
        #pragma unroll
        for (int off = 32; off > 0; off >>= 1) {
            #pragma unroll
            for (int rr6 = 0; rr6 < 6; ++rr6) {
                pacc[rr6][0] += __shfl_xor(pacc[rr6][0], off);
                pacc[rr6][1] += __shfl_xor(pacc[rr6][1], off);
            }
        }
        if (lane == 0) {
            #pragma unroll
            for (int rr6 = 0; rr6 < 6; ++rr6) {
                ghs[w * 6 + rr6][0] = pacc[rr6][0];
                ghs[w * 6 + rr6][1] = pacc[rr6][1];
            }
        }
        __syncthreads();

        // ---- pointwise update; tagged publish + immediate flag (no ack) ----
        if (tid < 16) {
            const float hr  = ghs[j][bb]      + bh[j];
            const float hz  = ghs[8 + j][bb]  + bh[8 + j];
            const float hnv = ghs[16 + j][bb] + bh[16 + j];
            const float rg = 1.f / (1.f + __expf(-(ir + hr)));
            const float zg = 1.f / (1.f + __expf(-(iz + hz)));
            const float ng = tanhf(inn + rg * hnv);
            const float hnew = (1.f - zg) * ng + zg * hprev;
            hprev = hnew;
            const int row = (bb << 10) | t;
            states[(size_t)row * 1024 + u0 + j] = hnew;
            uint2 pk;
            pk.x = __float_as_uint(hnew);
            pk.y = (unsigned)(t + 1);
            char* daddr = slotW + (((bb << 10) + u0 + j) << 3);
            asm volatile("global_store_dwordx2 %0, %1, off sc0 sc1"
                         :: "v"(daddr), "v"(pk) : "memory");
        }
        if (tid == 0)
            __hip_atomic_store(&flags[wg << 5], t + 1,
                               __ATOMIC_RELAXED, __HIP_MEMORY_SCOPE_AGENT);
        // tag validation replaces the vmcnt(0) write-ack round trip.
    }
}

// ---------------- gate = sigmoid(states @ Wg^T + bg), one wave per row ----------------
__global__ __launch_bounds__(256) void gate_kernel(
    const float* __restrict__ states, const float* __restrict__ Wg,
    const float* __restrict__ bg, float* __restrict__ gate)
{
    const int w = threadIdx.x >> 6, lane = threadIdx.x & 63;
    const int row = blockIdx.x * 4 + w;
    const float4* sr = (const float4*)(states + (size_t)row * 1024);
    const float4* wr = (const float4*)Wg;
    float p = 0.f;
    for (int c = 0; c < 4; ++c) {
        const float4 sv = sr[c * 64 + lane];
        const float4 wv = wr[c * 64 + lane];
        p += sv.x * wv.x + sv.y * wv.y + sv.z * wv.z + sv.w * wv.w;
    }
    for (int off = 32; off > 0; off >>= 1) p += __shfl_xor(p, off);
    if (lane == 0) gate[row] = 1.f / (1.f + __expf(-(p + bg[0])));
}

// ---------------- combined = base + gate * residual ----------------
__global__ __launch_bounds__(256) void combined_kernel(
    const float* __restrict__ base, const float* __restrict__ resid,
    const float* __restrict__ gate, float* __restrict__ comb)
{
    const int idx = blockIdx.x * 256 + threadIdx.x;
    const int row = idx >> 9;
    comb[idx] = base[idx] + gate[row] * resid[idx];
}

// ---------------- attention + scatter into logits ----------------
__global__ __launch_bounds__(256) void attn_scatter(
    const float* __restrict__ q,      // [2048][256]
    const float* __restrict__ kT,     // [2][256][1024]
    const float* __restrict__ gate,   // [2048]
    const float* __restrict__ mscale, // [1]
    const int* __restrict__ ids,      // [2][1024]
    float* __restrict__ out)          // [2][1024][32000]
{
    const int i = blockIdx.x, b = blockIdx.y, t = threadIdx.x;
    if (i == 0) return;
    __shared__ float qs[256];
    __shared__ float red[256];

    qs[t] = q[((size_t)((b << 10) | i)) * 256 + t];
    __syncthreads();

    const int j0 = t * 4;
    float s[4] = {0.f, 0.f, 0.f, 0.f};
    const float* kb = kT + (size_t)b * 256 * 1024;
    if (j0 < i) {
        for (int kk = 0; kk < 256; ++kk) {
            const float qv = qs[kk];
            const float4 kv = *(const float4*)(kb + (size_t)kk * 1024 + j0);
            s[0] += qv * kv.x; s[1] += qv * kv.y; s[2] += qv * kv.z; s[3] += qv * kv.w;
        }
    }
    const float scale = 0.0625f;  // 1/sqrt(256)
    float mx = -1e30f;
    for (int e = 0; e < 4; ++e)
        if (j0 + e < i) { s[e] *= scale; mx = fmaxf(mx, s[e]); }

    red[t] = mx; __syncthreads();
    for (int o = 128; o > 0; o >>= 1) {
        if (t < o) red[t] = fmaxf(red[t], red[t + o]);
        __syncthreads();
    }
    const float m = red[0];
    __syncthreads();

    float p[4]; float ssum = 0.f;
    for (int e = 0; e < 4; ++e) {
        if (j0 + e < i) { p[e] = __expf(s[e] - m); ssum += p[e]; }
        else p[e] = 0.f;
    }
    red[t] = ssum; __syncthreads();
    for (int o = 128; o > 0; o >>= 1) {
        if (t < o) red[t] += red[t + o];
        __syncthreads();
    }
    const float denom = fmaxf(red[0], 1e-6f);
    const float g6 = gate[(b << 10) | i] * mscale[0] / denom;

    float* orow = out + ((size_t)((b << 10) | i)) * 32000;
    const int* idr = ids + (b << 10);
    for (int e = 0; e < 4; ++e)
        if (j0 + e < i) atomicAdd(&orow[idr[j0 + e]], p[e] * g6);
}

// ---------------- launch ----------------
extern "C" void kernel_launch(void* const* d_in, const int* in_sizes, int n_in,
                              void* d_out, int out_size, void* d_ws, size_t ws_size,
                              hipStream_t stream)
{
    const int*   ids     = (const int*)  d_in[0];
    const float* emb_W   = (const float*)d_in[1];
    const float* w_ih    = (const float*)d_in[2];
    const float* w_hh    = (const float*)d_in[3];
    const float* b_ih    = (const float*)d_in[4];
    const float* b_hh    = (const float*)d_in[5];
    const float* Wq      = (const float*)d_in[6];
    const float* bq      = (const float*)d_in[7];
    const float* Wk      = (const float*)d_in[8];
    const float* bk      = (const float*)d_in[9];
    const float* Wg      = (const float*)d_in[10];
    const float* bg      = (const float*)d_in[11];
    const float* W1      = (const float*)d_in[12];
    const float* b1      = (const float*)d_in[13];
    const float* W2      = (const float*)d_in[14];
    const float* b2      = (const float*)d_in[15];
    const float* Wr      = (const float*)d_in[16];
    const float* br      = (const float*)d_in[17];
    const float* mscale  = (const float*)d_in[18];
    const float* out_b   = (const float*)d_in[19];
    float* out = (float*)d_out;

    float* ws = (float*)d_ws;
    float* xp     = ws;                         // 2048*3072
    float* states = xp     + (size_t)2048 * 3072;
    float* hf     = states + (size_t)2048 * 1024;
    float* base   = hf     + (size_t)2048 * 2048;
    float* resid  = base   + (size_t)2048 * 512;
    float* qv     = resid  + (size_t)2048 * 512;
    float* kT     = qv     + (size_t)2048 * 256;
    float* comb   = kT     + (size_t)2 * 256 * 1024;
    float* gate   = comb   + (size_t)2048 * 512;
    float* hbuf2  = gate   + 2048;              // 8192 floats: 2 slots x 2048 x 8B
    int*   flags  = (int*)(hbuf2 + 8192);       // 128 padded flags (4096 ints)

    dim3 blk(256);

    gemm_bt<ACT_NONE, true, false><<<dim3(32, 48), blk, 0, stream>>>(
        emb_W, w_ih, b_ih, xp, ids, 2048, 3072, 512);

    init_ws<<<32, blk, 0, stream>>>(hbuf2, flags);
    gru_kernel<<<128, blk, 0, stream>>>(xp, w_hh, b_hh, states, hbuf2, flags);

    gemm_bt<ACT_RELU2, false, false><<<dim3(32, 32), blk, 0, stream>>>(
        states, W1, b1, hf, nullptr, 2048, 2048, 1024);

    gemm_bt<ACT_NONE, false, false><<<dim3(32, 8), blk, 0, stream>>>(
        hf, W2, b2, base, nullptr, 2048, 512, 2048);

    gemm_bt<ACT_RELU, false, false><<<dim3(32, 8), blk, 0, stream>>>(
        base, Wr, br, resid, nullptr, 2048, 512, 512);

    gate_kernel<<<512, blk, 0, stream>>>(states, Wg, bg, gate);

    gemm_bt<ACT_NONE, false, false><<<dim3(32, 4), blk, 0, stream>>>(
        states, Wq, bq, qv, nullptr, 2048, 256, 1024);
    gemm_bt<ACT_NONE, false, true><<<dim3(32, 4), blk, 0, stream>>>(
        states, Wk, bk, kT, nullptr, 2048, 256, 1024);

    combined_kernel<<<4096, blk, 0, stream>>>(base, resid, gate, comb);

    gemm_bt<ACT_NONE, false, false><<<dim3(32, 500), blk, 0, stream>>>(
        comb, emb_W, out_b, out, nullptr, 2048, 32000, 512);

    attn_scatter<<<dim3(1024, 2), blk, 0, stream>>>(qv, kT, gate, mscale, ids, out);
}